// Round 4
// baseline (412.956 us; speedup 1.0000x reference)
//
#include <hip/hip_runtime.h>

// Problem constants (from the reference): B=32, T=12, H=448, W=304.
constexpr int B  = 32;
constexpr int T  = 12;
constexpr int H  = 448;
constexpr int W  = 304;
constexpr int BT = B * T;                 // 384 planes
constexpr int HW = H * W;                 // 136192 = 256 * 532
constexpr long long TOTAL = (long long)BT * HW;   // 52,297,728
constexpr float SCALE_FACTOR = 1.0f;

constexpr int NTHREADS = 256;
constexpr int PLANES_PER_GROUP = 24;             // 384 = 16 * 24
constexpr int NGROUPS = BT / PLANES_PER_GROUP;   // 16
constexpr int SCHUNKS = HW / NTHREADS;           // 532 exactly
constexpr int NBLOCKS = SCHUNKS * NGROUPS;       // 8512
constexpr int UNROLL  = 8;                       // 16 scalar loads in flight

// Each block owns ONE 256-float spatial chunk and 24 consecutive planes.
// Scalar (dword) loads: a wave's load = 256 B contiguous = 4 cache lines,
// 1 VGPR each -> the compiler can cheaply keep 16 independent loads in
// flight, instead of 2 monolithic dwordx4 (16-line) loads.
__global__ __launch_bounds__(NTHREADS)
void wmse_partial(const float* __restrict__ pred,
                  const float* __restrict__ targ,
                  const int*   __restrict__ target_months,   // [BT], 1-based
                  const float* __restrict__ monthly_weights, // [12]
                  const float* __restrict__ area_w,          // [HW]
                  float* __restrict__ partials)              // [NBLOCKS]
{
    const int tid    = threadIdx.x;
    const int chunk  = blockIdx.x % SCHUNKS;   // fast-varying -> contiguous sweep
    const int group  = blockIdx.x / SCHUNKS;
    const int plane0 = group * PLANES_PER_GROUP;
    const int sp     = chunk * NTHREADS + tid; // spatial f32 index

    // Fold month weight as w^2; stage the block's 24 plane weights in LDS.
    __shared__ float w2s[PLANES_PER_GROUP];
    if (tid < PLANES_PER_GROUP) {
        float w = monthly_weights[target_months[plane0 + tid] - 1];
        w2s[tid] = w * w;
    }

    // One area^2 scalar per thread, in a register.
    const float av = area_w[sp];
    const float a2 = av * av;
    __syncthreads();

    const float* __restrict__ p = pred + (size_t)plane0 * HW + sp;
    const float* __restrict__ t = targ + (size_t)plane0 * HW + sp;

    float acc0 = 0.f, acc1 = 0.f, acc2 = 0.f, acc3 = 0.f;

    #pragma unroll 1
    for (int k = 0; k < PLANES_PER_GROUP; k += UNROLL) {
        // 16 independent scalar loads issued before any use.
        float pv[UNROLL], tv[UNROLL];
        #pragma unroll
        for (int j = 0; j < UNROLL; ++j) pv[j] = p[(size_t)j * HW];
        #pragma unroll
        for (int j = 0; j < UNROLL; ++j) tv[j] = t[(size_t)j * HW];

        float d, c;
        d = tv[0] - pv[0]; c = w2s[k + 0] * a2; acc0 = fmaf(c * d, d, acc0);
        d = tv[1] - pv[1]; c = w2s[k + 1] * a2; acc1 = fmaf(c * d, d, acc1);
        d = tv[2] - pv[2]; c = w2s[k + 2] * a2; acc2 = fmaf(c * d, d, acc2);
        d = tv[3] - pv[3]; c = w2s[k + 3] * a2; acc3 = fmaf(c * d, d, acc3);
        d = tv[4] - pv[4]; c = w2s[k + 4] * a2; acc0 = fmaf(c * d, d, acc0);
        d = tv[5] - pv[5]; c = w2s[k + 5] * a2; acc1 = fmaf(c * d, d, acc1);
        d = tv[6] - pv[6]; c = w2s[k + 6] * a2; acc2 = fmaf(c * d, d, acc2);
        d = tv[7] - pv[7]; c = w2s[k + 7] * a2; acc3 = fmaf(c * d, d, acc3);

        p += (size_t)UNROLL * HW;
        t += (size_t)UNROLL * HW;
    }

    float acc = (acc0 + acc1) + (acc2 + acc3);

    // Wave-64 reduce, then cross-wave via LDS.
    #pragma unroll
    for (int off = 32; off > 0; off >>= 1)
        acc += __shfl_down(acc, off);

    __shared__ float wsum[NTHREADS / 64];
    const int lane = tid & 63;
    const int wid  = tid >> 6;
    if (lane == 0) wsum[wid] = acc;
    __syncthreads();
    if (tid == 0) {
        float s = 0.0f;
        #pragma unroll
        for (int w2 = 0; w2 < NTHREADS / 64; ++w2) s += wsum[w2];
        partials[blockIdx.x] = s;
    }
}

// One block folds the NBLOCKS partials and writes the mean.
__global__ __launch_bounds__(NTHREADS)
void wmse_final(const float* __restrict__ partials, float* __restrict__ out)
{
    float acc = 0.0f;
    for (int i = threadIdx.x; i < NBLOCKS; i += blockDim.x)
        acc += partials[i];

    #pragma unroll
    for (int off = 32; off > 0; off >>= 1)
        acc += __shfl_down(acc, off);

    __shared__ float wsum[NTHREADS / 64];
    const int lane = threadIdx.x & 63;
    const int wid  = threadIdx.x >> 6;
    if (lane == 0) wsum[wid] = acc;
    __syncthreads();
    if (threadIdx.x == 0) {
        float s = 0.0f;
        #pragma unroll
        for (int w2 = 0; w2 < NTHREADS / 64; ++w2) s += wsum[w2];
        out[0] = s * (SCALE_FACTOR / (float)TOTAL);
    }
}

extern "C" void kernel_launch(void* const* d_in, const int* in_sizes, int n_in,
                              void* d_out, int out_size, void* d_ws, size_t ws_size,
                              hipStream_t stream) {
    const float* pred = (const float*)d_in[0];
    const float* targ = (const float*)d_in[1];
    const int*   tm   = (const int*)d_in[2];
    const float* mw   = (const float*)d_in[3];
    const float* aw   = (const float*)d_in[4];
    float* out = (float*)d_out;
    float* partials = (float*)d_ws;   // NBLOCKS * 4 B = 34 KB, rewritten every call

    wmse_partial<<<NBLOCKS, NTHREADS, 0, stream>>>(pred, targ, tm, mw, aw, partials);
    wmse_final<<<1, NTHREADS, 0, stream>>>(partials, out);
}

// Round 5
// 412.340 us; speedup vs baseline: 1.0015x; 1.0015x over previous
//
#include <hip/hip_runtime.h>

// Problem constants (from the reference): B=32, T=12, H=448, W=304.
constexpr int B  = 32;
constexpr int T  = 12;
constexpr int H  = 448;
constexpr int W  = 304;
constexpr int BT = B * T;                 // 384 planes
constexpr int HW = H * W;                 // 136192
constexpr int HW4 = HW / 4;               // 34048 float4s per plane = 256*133
constexpr long long TOTAL = (long long)BT * HW;   // 52,297,728
constexpr float SCALE_FACTOR = 1.0f;

constexpr int NTHREADS = 256;
constexpr int PLANES_PER_GROUP = 24;             // 384 = 16 * 24
constexpr int NGROUPS = BT / PLANES_PER_GROUP;   // 16
constexpr int CHUNKS  = HW4 / NTHREADS;          // 133 exactly
constexpr int NBLOCKS = CHUNKS * NGROUPS;        // 2128

// ---- forced software pipeline: raw loads + counted vmcnt ----
// hipcc refuses to keep >2-3 loads in flight from plain C++ (R1-R4:
// VGPR=28/40/32/20). Inline asm + counted s_waitcnt is the T4 pattern.
template<int N>
__device__ __forceinline__ void vm_wait() {
    asm volatile("s_waitcnt vmcnt(%0)" :: "n"(N) : "memory");
}

#define GLOAD(dst, addr) \
    asm volatile("global_load_dwordx4 %0, %1, off" : "=v"(dst) : "v"(addr))

__global__ __launch_bounds__(NTHREADS)
void wmse_partial(const float4* __restrict__ pred,
                  const float4* __restrict__ targ,
                  const int*    __restrict__ target_months,   // [BT], 1-based
                  const float*  __restrict__ monthly_weights, // [12]
                  const float4* __restrict__ area_w4,         // [HW4]
                  float* __restrict__ partials)               // [NBLOCKS]
{
    const int tid    = threadIdx.x;
    const int chunk  = blockIdx.x % CHUNKS;
    const int group  = blockIdx.x / CHUNKS;
    const int plane0 = group * PLANES_PER_GROUP;
    const int sp     = chunk * NTHREADS + tid;   // spatial float4 index

    __shared__ float w2s[PLANES_PER_GROUP];
    if (tid < PLANES_PER_GROUP) {
        float w = monthly_weights[target_months[plane0 + tid] - 1];
        w2s[tid] = w * w;
    }

    float4 a = area_w4[sp];
    const float a2x = a.x * a.x, a2y = a.y * a.y, a2z = a.z * a.z, a2w = a.w * a.w;
    __syncthreads();

    const float4* pp = pred + (size_t)plane0 * HW4 + sp;
    const float4* tp = targ + (size_t)plane0 * HW4 + sp;

    float accA = 0.0f, accB = 0.0f;

    // 6 pipeline slots, 12 dwordx4 outstanding in steady state.
    float4 p0, p1, p2, p3, p4, p5;
    float4 t0, t1, t2, t3, t4, t5;

#define ISSUE(slot, j) \
    GLOAD(p##slot, pp + (size_t)(j) * HW4); \
    GLOAD(t##slot, tp + (size_t)(j) * HW4)

#define CONSUME(slot, j) { \
    float d0 = t##slot.x - p##slot.x; \
    float d1 = t##slot.y - p##slot.y; \
    float d2 = t##slot.z - p##slot.z; \
    float d3 = t##slot.w - p##slot.w; \
    float sv = a2x * d0 * d0 + a2y * d1 * d1; \
    sv = fmaf(a2z * d2, d2, sv); \
    sv = fmaf(a2w * d3, d3, sv); \
    if ((j) & 1) accB = fmaf(w2s[(j)], sv, accB); \
    else         accA = fmaf(w2s[(j)], sv, accA); }

    // wait for pair k (12 -> 10 outstanding), consume it, refill the slot.
#define STEP_MAIN(slot, k) \
    vm_wait<10>(); __builtin_amdgcn_sched_barrier(0); \
    CONSUME(slot, k); ISSUE(slot, (k) + 6)

#define STEP_EPI(slot, k, VM) \
    vm_wait<VM>(); __builtin_amdgcn_sched_barrier(0); \
    CONSUME(slot, k)

    // Prologue: fill 6 slots (12 loads in flight).
    ISSUE(0, 0); ISSUE(1, 1); ISSUE(2, 2); ISSUE(3, 3); ISSUE(4, 4); ISSUE(5, 5);

    // Steady state: k = 0..17.
    STEP_MAIN(0, 0);  STEP_MAIN(1, 1);  STEP_MAIN(2, 2);
    STEP_MAIN(3, 3);  STEP_MAIN(4, 4);  STEP_MAIN(5, 5);
    STEP_MAIN(0, 6);  STEP_MAIN(1, 7);  STEP_MAIN(2, 8);
    STEP_MAIN(3, 9);  STEP_MAIN(4, 10); STEP_MAIN(5, 11);
    STEP_MAIN(0, 12); STEP_MAIN(1, 13); STEP_MAIN(2, 14);
    STEP_MAIN(3, 15); STEP_MAIN(4, 16); STEP_MAIN(5, 17);

    // Epilogue drain: counted, never early.
    STEP_EPI(0, 18, 10);
    STEP_EPI(1, 19, 8);
    STEP_EPI(2, 20, 6);
    STEP_EPI(3, 21, 4);
    STEP_EPI(4, 22, 2);
    STEP_EPI(5, 23, 0);

    float acc = accA + accB;

    // Wave-64 reduce, then cross-wave via LDS.
    #pragma unroll
    for (int off = 32; off > 0; off >>= 1)
        acc += __shfl_down(acc, off);

    __shared__ float wsum[NTHREADS / 64];
    const int lane = tid & 63;
    const int wid  = tid >> 6;
    if (lane == 0) wsum[wid] = acc;
    __syncthreads();
    if (tid == 0) {
        float s = 0.0f;
        #pragma unroll
        for (int w2 = 0; w2 < NTHREADS / 64; ++w2) s += wsum[w2];
        partials[blockIdx.x] = s;
    }
}

// One block folds the NBLOCKS partials and writes the mean.
__global__ __launch_bounds__(NTHREADS)
void wmse_final(const float* __restrict__ partials, float* __restrict__ out)
{
    float acc = 0.0f;
    for (int i = threadIdx.x; i < NBLOCKS; i += blockDim.x)
        acc += partials[i];

    #pragma unroll
    for (int off = 32; off > 0; off >>= 1)
        acc += __shfl_down(acc, off);

    __shared__ float wsum[NTHREADS / 64];
    const int lane = threadIdx.x & 63;
    const int wid  = threadIdx.x >> 6;
    if (lane == 0) wsum[wid] = acc;
    __syncthreads();
    if (threadIdx.x == 0) {
        float s = 0.0f;
        #pragma unroll
        for (int w2 = 0; w2 < NTHREADS / 64; ++w2) s += wsum[w2];
        out[0] = s * (SCALE_FACTOR / (float)TOTAL);
    }
}

extern "C" void kernel_launch(void* const* d_in, const int* in_sizes, int n_in,
                              void* d_out, int out_size, void* d_ws, size_t ws_size,
                              hipStream_t stream) {
    const float4* pred = (const float4*)d_in[0];
    const float4* targ = (const float4*)d_in[1];
    const int*    tm   = (const int*)d_in[2];
    const float*  mw   = (const float*)d_in[3];
    const float4* aw   = (const float4*)d_in[4];
    float* out = (float*)d_out;
    float* partials = (float*)d_ws;   // NBLOCKS * 4 B, rewritten every call

    wmse_partial<<<NBLOCKS, NTHREADS, 0, stream>>>(pred, targ, tm, mw, aw, partials);
    wmse_final<<<1, NTHREADS, 0, stream>>>(partials, out);
}